// Round 9
// baseline (58.553 us; speedup 1.0000x reference)
//
#include <hip/hip_runtime.h>
#include <hip/hip_bf16.h>
#include <math.h>

typedef __attribute__((ext_vector_type(8))) short short8;
typedef __attribute__((ext_vector_type(4))) float f32x4;
typedef __attribute__((ext_vector_type(2))) float f32x2;

// ---------------- factorial tables (fp32) -------------------------
__constant__ float c_fact[20] = {
    1.0f, 1.0f, 2.0f, 6.0f, 24.0f, 120.0f, 720.0f, 5040.0f, 40320.0f, 362880.0f,
    3628800.0f, 39916800.0f, 479001600.0f, 6227020800.0f, 87178291200.0f,
    1307674368000.0f, 20922789888000.0f, 355687428096000.0f,
    6402373705728000.0f, 121645100408832000.0f};
__constant__ float c_invf[20] = {
    1.0f, 1.0f, 0.5f, 0.16666666666666666f, 0.041666666666666664f,
    0.008333333333333333f, 0.001388888888888889f, 1.984126984126984e-4f,
    2.48015873015873e-5f, 2.755731922398589e-6f, 2.755731922398589e-7f,
    2.505210838544172e-8f, 2.08767569878681e-9f, 1.6059043836821613e-10f,
    1.1470745597729725e-11f, 7.647163731819816e-13f, 4.779477332387385e-14f,
    2.8114572543455206e-15f, 1.5619206968586225e-16f, 8.22063524662433e-18f};

__device__ float cgd(int j1, int m1, int j2, int m2, int j3, int m3) {
  if (m1 + m2 != m3) return 0.0f;
  float pre = (float)(2 * j3 + 1) * c_fact[j1 + j2 - j3] * c_fact[j1 - j2 + j3] *
              c_fact[-j1 + j2 + j3] * c_invf[j1 + j2 + j3 + 1];
  pre *= c_fact[j1 + m1] * c_fact[j1 - m1] * c_fact[j2 + m2] * c_fact[j2 - m2] *
         c_fact[j3 + m3] * c_fact[j3 - m3];
  int kmin = max(0, max(j2 - j3 - m1, j1 - j3 + m2));
  int kmax = min(j1 + j2 - j3, min(j1 - m1, j2 + m2));
  float s = 0.0f;
  for (int k = kmin; k <= kmax; ++k) {
    float d = c_invf[k] * c_invf[j1 + j2 - j3 - k] * c_invf[j1 - m1 - k] *
              c_invf[j2 + m2 - k] * c_invf[j3 - j2 + m1 + k] * c_invf[j3 - j1 - m2 + k];
    s += ((k & 1) ? -d : d);
  }
  return sqrtf(pre) * s;
}

__device__ float wstd(int l1, int l2, int l3, int i, int j, int k) {
  int m1 = i - l1, m2 = j - l2, m3 = k - l3;
  if (m1 + m2 + m3 != 0) return 0.0f;
  int e = l1 - l2 - m3;
  float sgn = (e & 1) ? -1.0f : 1.0f;
  return sgn * (1.0f / sqrtf((float)(2 * l3 + 1))) * cgd(l1, m1, l2, m2, l3, -m3);
}

__device__ int qrow(int l, int a, int idx[2], float vr[2], float vi[2]) {
  const float s2 = 0.70710678118654752440f;
  int m = a - l;
  if (m == 0) { idx[0] = l; vr[0] = 1.0f; vi[0] = 0.0f; return 1; }
  if (m > 0) {
    idx[0] = l + m; vr[0] = (m & 1) ? -s2 : s2; vi[0] = 0.0f;
    idx[1] = l - m; vr[1] = s2;                 vi[1] = 0.0f;
    return 2;
  }
  int mm = -m;
  idx[0] = l - mm; vr[0] = 0.0f; vi[0] = s2;
  idx[1] = l + mm; vr[1] = 0.0f; vi[1] = (mm & 1) ? s2 : -s2;
  return 2;
}

__device__ float w3j_real(int l1, int l2, int l3, int a, int b, int c) {
  int i1[2], i2[2], i3[2];
  float r1[2], s1[2], r2[2], s2v[2], r3[2], s3[2];
  int n1 = qrow(l1, a, i1, r1, s1);
  int n2 = qrow(l2, b, i2, r2, s2v);
  int n3 = qrow(l3, c, i3, r3, s3);
  float re = 0.0f;
  for (int x = 0; x < n1; ++x)
    for (int y = 0; y < n2; ++y)
      for (int z = 0; z < n3; ++z) {
        float w = wstd(l1, l2, l3, i1[x], i2[y], i3[z]);
        if (w == 0.0f) continue;
        float pr = r1[x] * r2[y] - s1[x] * s2v[y];
        float pi = r1[x] * s2v[y] + s1[x] * r2[y];
        float qr = pr * r3[z] - pi * s3[z];
        re += qr * w;
      }
  int L = l1 + l2 + l3;
  return ((L & 3) == 0) ? re : -re;
}

__device__ float sh_val(int k, int col) {
  const float PI_ = 3.14159265358979323846f;
  float sgn = (k == 0 || k == 3) ? 1.0f : -1.0f;
  if (col == 0) return 0.5f / sqrtf(PI_);
  if (col == 1) return sgn * 0.25f * sqrtf(15.0f / PI_);
  if (col == 3) return -0.25f * sqrtf(5.0f / PI_);
  return 0.0f;
}

__device__ __forceinline__ unsigned short bf16u(float x) {
  __hip_bfloat16 h = __float2bfloat16(x);
  return __builtin_bit_cast(unsigned short, h);
}
__device__ __forceinline__ float b2f(unsigned short u) {
  unsigned int v = ((unsigned int)u) << 16;
  return __builtin_bit_cast(float, v);
}

// ws layout: bytes [0, 22528) = W3G fp8 frag-swizzled;
//            ushort offset 11264..15360 = M3G bf16 (4096 ush)
__global__ void eq_setup(const float* __restrict__ w_agg, const float* __restrict__ w_tp,
                         const int* __restrict__ ph, const int* __restrict__ pw,
                         float* __restrict__ out, long long tail_off,
                         unsigned short* __restrict__ ws) {
  int gid = blockIdx.x * 256 + threadIdx.x;
  if (gid == 0) {
    out[tail_off]     = (float)(ph[0] * 4);
    out[tail_off + 1] = (float)(pw[0] * 4);
  }
  if (gid < 22528) {  // W3G: fp8 B-fragment byte for K2
    int a = gid >> 10;
    int rem = gid & 1023;
    int nt = rem >> 9;
    int l = (rem >> 3) & 63;
    int e = rem & 7;
    int b = ((l >> 4) << 3) + e;   // k index (contraction over b)
    int c = nt * 16 + (l & 15);    // output col
    float v = 0.f;
    if (b < 22 && c < 22) {
      int l1 = (a < 9) ? 4 : 6, l2 = (b < 9) ? 4 : 6, l3 = (c < 9) ? 4 : 6;
      int a_ = (a < 9) ? a : a - 9, b_ = (b < 9) ? b : b - 9, c_ = (c < 9) ? c : c - 9;
      int idx = ((l1 == 6) ? 4 : 0) + ((l2 == 6) ? 2 : 0) + ((l3 == 6) ? 1 : 0);
      float alpha = sqrtf((float)(2 * l3 + 1) * 0.25f);
      v = w_tp[idx] * alpha * w3j_real(l1, l2, l3, a_, b_, c_);
    }
    int pk = __builtin_amdgcn_cvt_pk_fp8_f32(v, 0.f, 0, 0);
    ((unsigned char*)ws)[gid] = (unsigned char)(pk & 0xff);
  } else if (gid < 26624) {  // M3G: bf16 B-fragment element for K1
    int s = gid - 22528;
    int km = s >> 10;
    int rem = s & 1023;
    int nt = rem >> 9;
    int l = (rem >> 3) & 63;
    int e = rem & 7;
    int a = ((l >> 4) << 3) + e;   // k index (contraction over a)
    int c = nt * 16 + (l & 15);    // output col
    float v = 0.f;
    if (a < 22 && c < 22) {
      int l1 = (a < 9) ? 4 : 6, l3 = (c < 9) ? 4 : 6;
      int a_ = (a < 9) ? a : a - 9, c_ = (c < 9) ? c : c - 9;
      float acc = 0.0f;
      float alpha = sqrtf((float)(2 * l3 + 1) / 3.0f);
      if (l1 == l3) {
        int i = (l1 == 4) ? 0 : 3;
        acc += w_agg[i] * alpha * sh_val(km, 0) * w3j_real(l1, 0, l3, a_, 0, c_);
      }
      {
        int i = (l1 == 4) ? ((l3 == 4) ? 1 : 2) : ((l3 == 4) ? 4 : 5);
        float t = 0.0f;
        for (int bb = 0; bb < 5; ++bb) {
          float shv = sh_val(km, 1 + bb);
          if (shv != 0.0f) t += shv * w3j_real(l1, 2, l3, a_, bb, c_);
        }
        acc += w_agg[i] * alpha * t;
      }
      v = acc;
    }
    ws[11264 + s] = bf16u(v);
  }
}

#define WAVE_LDS_FENCE() do { \
    asm volatile("s_waitcnt lgkmcnt(0)" ::: "memory"); \
    __builtin_amdgcn_sched_barrier(0); } while (0)

// ------- main kernel: 256 threads (4 waves), wave-autonomous, NO barriers.
// ------- Each wave owns 8 coarse cells (two groups of 4). W+M in REGISTERS;
// ------- LDS only for per-wave F (18px) and ctx/vout scratch. -------
__global__ __launch_bounds__(256, 3) void eq_main(
    const float* __restrict__ f4, const float* __restrict__ f6,
    const int* __restrict__ ph, const int* __restrict__ pw,
    const unsigned short* __restrict__ ws, float* __restrict__ out) {
  const int H = ph[0], Wc = pw[0];
  const int bx = (Wc + 31) >> 5;
  const long long ntiles = (long long)bx * H;
  const int Wr = Wc << 2;
  const long long Npix = (long long)H * Wc * 16;
  float* out6 = out + Npix * 9;

  // per-wave LDS slot (ush): F [0,432) = 18px x 24ch; C0 [448,832); C1 [832,1216)
  __shared__ __align__(16) unsigned short LDS[4864];  // 4 waves x 1216 ush = 9728 B

  const int tid = threadIdx.x;
  const int wv = tid >> 6;
  const int l = tid & 63;
  const long long t = blockIdx.x;
  if (t >= ntiles) return;  // no barriers anywhere -> early exit is safe

  const int y0 = (int)(t / bx);
  const int x0 = (int)(t - (long long)y0 * bx) << 5;
  const int cwB = x0 + (wv << 3);        // wave's first coarse col (8 cells)
  const int WOFF = wv * 1216;

  // ---- M fragments -> regs (issued first; needed first, in K1) ----
  short8 mb[8];
  {
    const unsigned short* msrc = ws + 11264;
#pragma unroll
    for (int i = 0; i < 8; ++i) mb[i] = *(const short8*)(msrc + i * 512 + l * 8);
  }

  // ---- F staging: 2 rows x 9 cols (8 + halo) x 22ch -> bf16 LDS ----
#pragma unroll
  for (int it = 0; it < 4; ++it) {
    int e = it * 64 + l;
    if (e < 198) {
      int px = e / 11, pr = e - px * 11;
      int dyR = px / 9, col = px - dyR * 9;
      int yy = min(y0 + dyR, H - 1);
      int xx = min(cwB + col, Wc - 1);
      long long p = (long long)yy * Wc + xx;
      int ca = 2 * pr;
      float v0 = (ca < 9) ? f4[p * 9 + ca] : f6[p * 13 + ca - 9];
      float v1 = (ca + 1 < 9) ? f4[p * 9 + ca + 1] : f6[p * 13 + ca - 8];
      unsigned int pk = (unsigned int)bf16u(v0) | ((unsigned int)bf16u(v1) << 16);
      *(unsigned int*)&LDS[WOFF + px * 24 + ca] = pk;
    } else if (e < 216) {
      *(unsigned int*)&LDS[WOFF + (e - 198) * 24 + 22] = 0u;  // pad ch 22,23
    }
  }

  // ---- W fragments -> regs (issued LAST; latency hides under K1) ----
  long Wr_[44];
  {
    const char* wsb = (const char*)ws;
#pragma unroll
    for (int ap = 0; ap < 11; ++ap) {
#pragma unroll
      for (int j = 0; j < 4; ++j)
        Wr_[ap * 4 + j] = *(const long*)(wsb + ap * 2048 + j * 512 + l * 8);
    }
  }

  WAVE_LDS_FENCE();  // F ds_writes drained (wave-local)

  const int l15 = l & 15;
  const int lg = l >> 4;          // 0..3
  const int q = l15 & 3;          // cls of this lane's A-row
  const int lcell = l15 >> 2;     // cell (0..3) within group of this lane's A-row
  const int a0 = lg << 3;         // fragment k-offset: 0,8,16,24

  // ---- K1 for both groups: ctx = sum_k X_k * M_k ; transpose into C0/C1 ----
#pragma unroll
  for (int g = 0; g < 2; ++g) {
    const int COFF = WOFF + 448 + g * 384;
    f32x4 c0 = {0.f, 0.f, 0.f, 0.f}, c1 = {0.f, 0.f, 0.f, 0.f};
#pragma unroll
    for (int km = 0; km < 4; ++km) {
      short8 av = (short8)0;
      if (a0 < 24) {
        int dy = (km >> 1) & (q >> 1);
        int dx = km & q & 1;
        av = *(const short8*)&LDS[WOFF + (dy * 9 + (g << 2) + lcell + dx) * 24 + a0];
      }
      c0 = __builtin_amdgcn_mfma_f32_16x16x32_bf16(av, mb[2 * km], c0, 0, 0, 0);
      c1 = __builtin_amdgcn_mfma_f32_16x16x32_bf16(av, mb[2 * km + 1], c1, 0, 0, 0);
    }
    // transpose (col=pixel(l15), row=chan)
#pragma unroll
    for (int r = 0; r < 4; ++r) {
      LDS[COFF + l15 * 24 + (lg << 2) + r] = bf16u(c0[r]);
      int ch1 = 16 + (lg << 2) + r;
      if (ch1 < 22) LDS[COFF + l15 * 24 + ch1] = bf16u(c1[r]);
    }
    if (lg == 0) *(unsigned int*)&LDS[COFF + l15 * 24 + 22] = 0u;  // pad
  }
  WAVE_LDS_FENCE();  // ctx visible (wave-local)

  // ---- K2 + writer per group ----
#pragma unroll
  for (int g = 0; g < 2; ++g) {
    const int COFF = WOFF + 448 + g * 384;
    const int frow = WOFF + ((g << 2) + lcell) * 24;

    // A-source: ctx row (8 chans at a0) + packed F row + residuals
    f32x2 cv2[4];
    {
      short8 cvb = (short8)0;
      if (a0 < 24) cvb = *(const short8*)&LDS[COFF + l15 * 24 + a0];
#pragma unroll
      for (int j = 0; j < 4; ++j) {
        cv2[j][0] = b2f((unsigned short)cvb[2 * j]);
        cv2[j][1] = b2f((unsigned short)cvb[2 * j + 1]);
      }
    }
    unsigned int fvp[11];
    {
      const unsigned int* fp = (const unsigned int*)&LDS[frow];
#pragma unroll
      for (int j = 0; j < 11; ++j) fvp[j] = fp[j];
    }
    const float r4 = b2f(LDS[WOFF + ((g << 2) + lg) * 24 + l15]);
    const float r6 = (l15 < 6) ? b2f(LDS[WOFF + ((g << 2) + lg) * 24 + 16 + l15]) : 0.f;

    // K2 (fp8, W in regs): out = sum_a F[a] * (ctx . W[a])
    f32x4 oE0 = {0.f, 0.f, 0.f, 0.f}, oE1 = {0.f, 0.f, 0.f, 0.f};
    f32x4 oO0 = {0.f, 0.f, 0.f, 0.f}, oO1 = {0.f, 0.f, 0.f, 0.f};
#pragma unroll
    for (int ap = 0; ap < 11; ++ap) {
      const float sE = __builtin_bit_cast(float, fvp[ap] << 16);
      const float sO = __builtin_bit_cast(float, fvp[ap] & 0xffff0000u);
      {
        const f32x2 s2 = {sE, sE};
        f32x2 p0 = cv2[0] * s2, p1 = cv2[1] * s2, p2 = cv2[2] * s2, p3 = cv2[3] * s2;
        int lo = __builtin_amdgcn_cvt_pk_fp8_f32(p0[0], p0[1], 0, 0);
        lo = __builtin_amdgcn_cvt_pk_fp8_f32(p1[0], p1[1], lo, 1);
        int hi = __builtin_amdgcn_cvt_pk_fp8_f32(p2[0], p2[1], 0, 0);
        hi = __builtin_amdgcn_cvt_pk_fp8_f32(p3[0], p3[1], hi, 1);
        long av = (long)(((unsigned long long)(unsigned int)hi << 32) | (unsigned int)lo);
        oE0 = __builtin_amdgcn_mfma_f32_16x16x32_fp8_fp8(av, Wr_[ap * 4 + 0], oE0, 0, 0, 0);
        oE1 = __builtin_amdgcn_mfma_f32_16x16x32_fp8_fp8(av, Wr_[ap * 4 + 1], oE1, 0, 0, 0);
      }
      {
        const f32x2 s2 = {sO, sO};
        f32x2 p0 = cv2[0] * s2, p1 = cv2[1] * s2, p2 = cv2[2] * s2, p3 = cv2[3] * s2;
        int lo = __builtin_amdgcn_cvt_pk_fp8_f32(p0[0], p0[1], 0, 0);
        lo = __builtin_amdgcn_cvt_pk_fp8_f32(p1[0], p1[1], lo, 1);
        int hi = __builtin_amdgcn_cvt_pk_fp8_f32(p2[0], p2[1], 0, 0);
        hi = __builtin_amdgcn_cvt_pk_fp8_f32(p3[0], p3[1], hi, 1);
        long av = (long)(((unsigned long long)(unsigned int)hi << 32) | (unsigned int)lo);
        oO0 = __builtin_amdgcn_mfma_f32_16x16x32_fp8_fp8(av, Wr_[ap * 4 + 2], oO0, 0, 0, 0);
        oO1 = __builtin_amdgcn_mfma_f32_16x16x32_fp8_fp8(av, Wr_[ap * 4 + 3], oO1, 0, 0, 0);
      }
    }

    // epilogue: vout = out + residual F (overwrites ctx slot)
#pragma unroll
    for (int r = 0; r < 4; ++r) {
      int n = (lg << 2) + r;
      LDS[COFF + n * 24 + l15] = bf16u(oE0[r] + oO0[r] + r4);
      if (l15 < 6) LDS[COFF + n * 24 + 16 + l15] = bf16u(oE1[r] + oO1[r] + r6);
    }
    WAVE_LDS_FENCE();

    // writer: lane = (ry, px) within the group's 4x16 HR patch
    {
      const int cwg = cwB + (g << 2);
      const int px = l & 15;
      const int ry = l >> 4;
      const int n = (px & ~3) | ((ry == 3) ? 2 : 0) | (((px & 3) == 3) ? 1 : 0);
      const short8 r0 = *(const short8*)&LDS[COFF + n * 24];
      const short8 r1 = *(const short8*)&LDS[COFF + n * 24 + 8];
      const short8 r2 = *(const short8*)&LDS[COFF + n * 24 + 16];
      const int hrx = (cwg << 2) + px;
      if (hrx < Wr) {
        const long long rowb = (long long)((y0 << 2) + ry) * Wr + hrx;
        float* o4 = out + rowb * 9;
#pragma unroll
        for (int j = 0; j < 8; ++j) o4[j] = b2f((unsigned short)r0[j]);
        o4[8] = b2f((unsigned short)r1[0]);
        float* o6 = out6 + rowb * 13;
#pragma unroll
        for (int j = 0; j < 7; ++j) o6[j] = b2f((unsigned short)r1[1 + j]);
#pragma unroll
        for (int j = 0; j < 6; ++j) o6[7 + j] = b2f((unsigned short)r2[j]);
      }
      WAVE_LDS_FENCE();  // writer ds_reads done before next group's epilogue
    }
  }
}

extern "C" void kernel_launch(void* const* d_in, const int* in_sizes, int n_in,
                              void* d_out, int out_size, void* d_ws, size_t ws_size,
                              hipStream_t stream) {
  const float* f4 = (const float*)d_in[0];
  const float* f6 = (const float*)d_in[1];
  const int* ph = (const int*)d_in[2];
  const int* pw = (const int*)d_in[3];
  const float* wagg = (const float*)d_in[4];
  const float* wtp = (const float*)d_in[5];
  float* out = (float*)d_out;
  unsigned short* wsu = (unsigned short*)d_ws;

  long long HW = (long long)in_sizes[0] / 9;
  long long tail = (long long)out_size - 2;

  eq_setup<<<104, 256, 0, stream>>>(wagg, wtp, ph, pw, out, tail, wsu);

  int S = (int)(sqrt((double)HW) + 0.5);
  long long nb;
  if ((long long)S * S == HW) {
    nb = (long long)((S + 31) / 32) * S;  // square image (the bench case)
  } else {
    nb = HW;  // conservative cover; excess blocks exit immediately (no barriers)
  }
  eq_main<<<(int)nb, 256, 0, stream>>>(f4, f6, ph, pw, wsu, out);
}

// Round 10
// 46.067 us; speedup vs baseline: 1.2710x; 1.2710x over previous
//
#include <hip/hip_runtime.h>
#include <hip/hip_bf16.h>
#include <math.h>

typedef __attribute__((ext_vector_type(8))) short short8;
typedef __attribute__((ext_vector_type(4))) float f32x4;
typedef __attribute__((ext_vector_type(2))) float f32x2;

// ---------------- factorial tables (fp32) -------------------------
__constant__ float c_fact[20] = {
    1.0f, 1.0f, 2.0f, 6.0f, 24.0f, 120.0f, 720.0f, 5040.0f, 40320.0f, 362880.0f,
    3628800.0f, 39916800.0f, 479001600.0f, 6227020800.0f, 87178291200.0f,
    1307674368000.0f, 20922789888000.0f, 355687428096000.0f,
    6402373705728000.0f, 121645100408832000.0f};
__constant__ float c_invf[20] = {
    1.0f, 1.0f, 0.5f, 0.16666666666666666f, 0.041666666666666664f,
    0.008333333333333333f, 0.001388888888888889f, 1.984126984126984e-4f,
    2.48015873015873e-5f, 2.755731922398589e-6f, 2.755731922398589e-7f,
    2.505210838544172e-8f, 2.08767569878681e-9f, 1.6059043836821613e-10f,
    1.1470745597729725e-11f, 7.647163731819816e-13f, 4.779477332387385e-14f,
    2.8114572543455206e-15f, 1.5619206968586225e-16f, 8.22063524662433e-18f};

__device__ float cgd(int j1, int m1, int j2, int m2, int j3, int m3) {
  if (m1 + m2 != m3) return 0.0f;
  float pre = (float)(2 * j3 + 1) * c_fact[j1 + j2 - j3] * c_fact[j1 - j2 + j3] *
              c_fact[-j1 + j2 + j3] * c_invf[j1 + j2 + j3 + 1];
  pre *= c_fact[j1 + m1] * c_fact[j1 - m1] * c_fact[j2 + m2] * c_fact[j2 - m2] *
         c_fact[j3 + m3] * c_fact[j3 - m3];
  int kmin = max(0, max(j2 - j3 - m1, j1 - j3 + m2));
  int kmax = min(j1 + j2 - j3, min(j1 - m1, j2 + m2));
  float s = 0.0f;
  for (int k = kmin; k <= kmax; ++k) {
    float d = c_invf[k] * c_invf[j1 + j2 - j3 - k] * c_invf[j1 - m1 - k] *
              c_invf[j2 + m2 - k] * c_invf[j3 - j2 + m1 + k] * c_invf[j3 - j1 - m2 + k];
    s += ((k & 1) ? -d : d);
  }
  return sqrtf(pre) * s;
}

__device__ float wstd(int l1, int l2, int l3, int i, int j, int k) {
  int m1 = i - l1, m2 = j - l2, m3 = k - l3;
  if (m1 + m2 + m3 != 0) return 0.0f;
  int e = l1 - l2 - m3;
  float sgn = (e & 1) ? -1.0f : 1.0f;
  return sgn * (1.0f / sqrtf((float)(2 * l3 + 1))) * cgd(l1, m1, l2, m2, l3, -m3);
}

__device__ int qrow(int l, int a, int idx[2], float vr[2], float vi[2]) {
  const float s2 = 0.70710678118654752440f;
  int m = a - l;
  if (m == 0) { idx[0] = l; vr[0] = 1.0f; vi[0] = 0.0f; return 1; }
  if (m > 0) {
    idx[0] = l + m; vr[0] = (m & 1) ? -s2 : s2; vi[0] = 0.0f;
    idx[1] = l - m; vr[1] = s2;                 vi[1] = 0.0f;
    return 2;
  }
  int mm = -m;
  idx[0] = l - mm; vr[0] = 0.0f; vi[0] = s2;
  idx[1] = l + mm; vr[1] = 0.0f; vi[1] = (mm & 1) ? s2 : -s2;
  return 2;
}

__device__ float w3j_real(int l1, int l2, int l3, int a, int b, int c) {
  int i1[2], i2[2], i3[2];
  float r1[2], s1[2], r2[2], s2v[2], r3[2], s3[2];
  int n1 = qrow(l1, a, i1, r1, s1);
  int n2 = qrow(l2, b, i2, r2, s2v);
  int n3 = qrow(l3, c, i3, r3, s3);
  float re = 0.0f;
  for (int x = 0; x < n1; ++x)
    for (int y = 0; y < n2; ++y)
      for (int z = 0; z < n3; ++z) {
        float w = wstd(l1, l2, l3, i1[x], i2[y], i3[z]);
        if (w == 0.0f) continue;
        float pr = r1[x] * r2[y] - s1[x] * s2v[y];
        float pi = r1[x] * s2v[y] + s1[x] * r2[y];
        float qr = pr * r3[z] - pi * s3[z];
        re += qr * w;
      }
  int L = l1 + l2 + l3;
  return ((L & 3) == 0) ? re : -re;
}

__device__ float sh_val(int k, int col) {
  const float PI_ = 3.14159265358979323846f;
  float sgn = (k == 0 || k == 3) ? 1.0f : -1.0f;
  if (col == 0) return 0.5f / sqrtf(PI_);
  if (col == 1) return sgn * 0.25f * sqrtf(15.0f / PI_);
  if (col == 3) return -0.25f * sqrtf(5.0f / PI_);
  return 0.0f;
}

__device__ __forceinline__ unsigned short bf16u(float x) {
  __hip_bfloat16 h = __float2bfloat16(x);
  return __builtin_bit_cast(unsigned short, h);
}
__device__ __forceinline__ float b2f(unsigned short u) {
  unsigned int v = ((unsigned int)u) << 16;
  return __builtin_bit_cast(float, v);
}

// ws layout: bytes [0, 22528) = W3G fp8 frag-swizzled;
//            ushort offset 11264..15360 = M3G bf16 (4096 ush)
__global__ void eq_setup(const float* __restrict__ w_agg, const float* __restrict__ w_tp,
                         const int* __restrict__ ph, const int* __restrict__ pw,
                         float* __restrict__ out, long long tail_off,
                         unsigned short* __restrict__ ws) {
  int gid = blockIdx.x * 256 + threadIdx.x;
  if (gid == 0) {
    out[tail_off]     = (float)(ph[0] * 4);
    out[tail_off + 1] = (float)(pw[0] * 4);
  }
  if (gid < 22528) {  // W3G: fp8 B-fragment byte for K2
    int a = gid >> 10;
    int rem = gid & 1023;
    int nt = rem >> 9;
    int l = (rem >> 3) & 63;
    int e = rem & 7;
    int b = ((l >> 4) << 3) + e;   // k index (contraction over b)
    int c = nt * 16 + (l & 15);    // output col
    float v = 0.f;
    if (b < 22 && c < 22) {
      int l1 = (a < 9) ? 4 : 6, l2 = (b < 9) ? 4 : 6, l3 = (c < 9) ? 4 : 6;
      int a_ = (a < 9) ? a : a - 9, b_ = (b < 9) ? b : b - 9, c_ = (c < 9) ? c : c - 9;
      int idx = ((l1 == 6) ? 4 : 0) + ((l2 == 6) ? 2 : 0) + ((l3 == 6) ? 1 : 0);
      float alpha = sqrtf((float)(2 * l3 + 1) * 0.25f);
      v = w_tp[idx] * alpha * w3j_real(l1, l2, l3, a_, b_, c_);
    }
    int pk = __builtin_amdgcn_cvt_pk_fp8_f32(v, 0.f, 0, 0);
    ((unsigned char*)ws)[gid] = (unsigned char)(pk & 0xff);
  } else if (gid < 26624) {  // M3G: bf16 B-fragment element for K1
    int s = gid - 22528;
    int km = s >> 10;
    int rem = s & 1023;
    int nt = rem >> 9;
    int l = (rem >> 3) & 63;
    int e = rem & 7;
    int a = ((l >> 4) << 3) + e;   // k index (contraction over a)
    int c = nt * 16 + (l & 15);    // output col
    float v = 0.f;
    if (a < 22 && c < 22) {
      int l1 = (a < 9) ? 4 : 6, l3 = (c < 9) ? 4 : 6;
      int a_ = (a < 9) ? a : a - 9, c_ = (c < 9) ? c : c - 9;
      float acc = 0.0f;
      float alpha = sqrtf((float)(2 * l3 + 1) / 3.0f);
      if (l1 == l3) {
        int i = (l1 == 4) ? 0 : 3;
        acc += w_agg[i] * alpha * sh_val(km, 0) * w3j_real(l1, 0, l3, a_, 0, c_);
      }
      {
        int i = (l1 == 4) ? ((l3 == 4) ? 1 : 2) : ((l3 == 4) ? 4 : 5);
        float t = 0.0f;
        for (int bb = 0; bb < 5; ++bb) {
          float shv = sh_val(km, 1 + bb);
          if (shv != 0.0f) t += shv * w3j_real(l1, 2, l3, a_, bb, c_);
        }
        acc += w_agg[i] * alpha * t;
      }
      v = acc;
    }
    ws[11264 + s] = bf16u(v);
  }
}

__device__ __forceinline__ void load_lds16(const unsigned int* g, unsigned int* l) {
  __builtin_amdgcn_global_load_lds(
      (const __attribute__((address_space(1))) unsigned int*)g,
      (__attribute__((address_space(3))) unsigned int*)l, 16, 0, 0);
}

#define WAVE_LDS_FENCE() do { \
    asm volatile("s_waitcnt lgkmcnt(0)" ::: "memory"); \
    __builtin_amdgcn_sched_barrier(0); } while (0)

// ------- main kernel: 32 cells/block, 512 threads; each WAVE owns 4 cells.
// ------- W fp8 in LDS (block-shared); M from global; fp32 pixel-staged writer
// ------- with contiguous dwordx4 stores. One block barrier. -------
__global__ __launch_bounds__(512, 6) void eq_main(
    const float* __restrict__ f4, const float* __restrict__ f6,
    const int* __restrict__ ph, const int* __restrict__ pw,
    const unsigned short* __restrict__ ws, float* __restrict__ out) {
  const int H = ph[0], Wc = pw[0];
  const int bx = (Wc + 31) >> 5;
  const long long ntiles = (long long)bx * H;
  const int Wr = Wc << 2;
  const long long Npix = (long long)H * Wc * 16;
  float* out6 = out + Npix * 9;

  // LDS (ush units): W fp8 [0, 11264); per-wave slot 1472 ush at 11264+wv*1472:
  //   phase 1: F bf16 [0,240) (10px x 24ch), ctx f32 at ush [256,1024)
  //   phase 2: PX4 f32 [2][16][9] at f32 0..288, PX6 f32 [2][16][13] at 288..704
  __shared__ __align__(16) unsigned short LDS[23040];  // 46080 B -> 3 blocks/CU

  const int tid = threadIdx.x;
  const int wv = tid >> 6;
  const int l = tid & 63;
  const long long t = blockIdx.x;
  if (t >= ntiles) return;  // uniform per block (before barrier) -> safe

  const int y0 = (int)(t / bx);
  const int x0 = (int)(t - (long long)y0 * bx) << 5;
  const int cw0 = x0 + (wv << 2);       // wave's first coarse cell col
  const int SLOT = 11264 + wv * 1472;   // ush index

  // ---- stage W table via async global->LDS DMA (22 KiB, linear) ----
  {
    const unsigned int* src = (const unsigned int*)ws;
    unsigned int* dst = (unsigned int*)LDS;
#pragma unroll
    for (int i = 0; i < 3; ++i) {
      int chunk = i * 8 + wv;  // wave-uniform; 1 KiB per chunk
      if (chunk < 22) load_lds16(src + chunk * 256 + l * 4, dst + chunk * 256);
    }
  }

  // ---- K1 M-fragments straight from global (L2-hot, bf16) ----
  short8 mb[8];
  {
    const unsigned short* msrc = ws + 11264;
#pragma unroll
    for (int i = 0; i < 8; ++i) mb[i] = *(const short8*)(msrc + i * 512 + l * 8);
  }

  // ---- per-wave feature staging: 2 rows x 5 cols x 22 ch -> bf16 LDS ----
#pragma unroll
  for (int k = 0; k < 2; ++k) {
    int e = k * 64 + l;
    if (e < 110) {
      int px = e / 11, pr = e - px * 11;
      int dyR = px / 5, col = px - dyR * 5;
      int yy = min(y0 + dyR, H - 1);
      int xx = min(cw0 + col, Wc - 1);
      long long p = (long long)yy * Wc + xx;
      int ca = 2 * pr;
      float v0 = (ca < 9) ? f4[p * 9 + ca] : f6[p * 13 + ca - 9];
      float v1 = (ca + 1 < 9) ? f4[p * 9 + ca + 1] : f6[p * 13 + ca - 8];
      unsigned int pk = (unsigned int)bf16u(v0) | ((unsigned int)bf16u(v1) << 16);
      *(unsigned int*)&LDS[SLOT + px * 24 + ca] = pk;
    } else if (e < 120) {
      *(unsigned int*)&LDS[SLOT + (e - 110) * 24 + 22] = 0u;  // pad ch 22,23
    }
  }

  __syncthreads();  // the ONLY block barrier: W DMA + F staging drained

  const int l15 = l & 15;
  const int lg = l >> 4;          // 0..3
  const int q = l15 & 3;          // cls of this lane's A-row
  const int lcell = l15 >> 2;     // cell (0..3) of this lane's A-row
  const int a0 = lg << 3;         // fragment k-offset: 0,8,16,24

  // ---- K1: ctx = sum_k X_k * M_k (16 rows = 4 cells x 4 cls, bf16 MFMA) ----
  f32x4 c0 = {0.f, 0.f, 0.f, 0.f}, c1 = {0.f, 0.f, 0.f, 0.f};
#pragma unroll
  for (int km = 0; km < 4; ++km) {
    short8 av = (short8)0;
    if (a0 < 24) {
      int dy = (km >> 1) & (q >> 1);
      int dx = km & q & 1;
      av = *(const short8*)&LDS[SLOT + (dy * 5 + lcell + dx) * 24 + a0];
    }
    c0 = __builtin_amdgcn_mfma_f32_16x16x32_bf16(av, mb[2 * km], c0, 0, 0, 0);
    c1 = __builtin_amdgcn_mfma_f32_16x16x32_bf16(av, mb[2 * km + 1], c1, 0, 0, 0);
  }

  // ---- gather F-dependent values (before PX overlays F later) ----
  unsigned int fvp[11];  // packed bf16 pairs of center-pixel F row
  {
    const unsigned int* fp = (const unsigned int*)&LDS[SLOT + lcell * 24];
#pragma unroll
    for (int j = 0; j < 11; ++j) fvp[j] = fp[j];
  }
  const float r4 = b2f(LDS[SLOT + lg * 24 + l15]);
  const float r6 = (l15 < 6) ? b2f(LDS[SLOT + lg * 24 + 16 + l15]) : 0.f;

  // ---- ctx transpose as fp32 (col=pixel(l15), row=chan) ----
  float* ctxf = (float*)&LDS[SLOT + 256];
#pragma unroll
  for (int r = 0; r < 4; ++r) {
    ctxf[l15 * 24 + (lg << 2) + r] = c0[r];
    int ch1 = 16 + (lg << 2) + r;
    if (ch1 < 22) ctxf[l15 * 24 + ch1] = c1[r];
  }
  if (lg == 0) { ctxf[l15 * 24 + 22] = 0.f; ctxf[l15 * 24 + 23] = 0.f; }
  WAVE_LDS_FENCE();

  // ---- K2 A-source: ctx row (8 chans at a0) as float2 pairs ----
  f32x2 cv2[4];
  {
    f32x4 lo = {0.f, 0.f, 0.f, 0.f}, hi = {0.f, 0.f, 0.f, 0.f};
    if (a0 < 24) {
      lo = *(const f32x4*)(ctxf + l15 * 24 + a0);
      hi = *(const f32x4*)(ctxf + l15 * 24 + a0 + 4);
    }
    cv2[0][0] = lo[0]; cv2[0][1] = lo[1];
    cv2[1][0] = lo[2]; cv2[1][1] = lo[3];
    cv2[2][0] = hi[0]; cv2[2][1] = hi[1];
    cv2[3][0] = hi[2]; cv2[3][1] = hi[3];
  }
  WAVE_LDS_FENCE();  // F/ctx reads complete before PX overlays the slot

  // ---- K2 (fp8): out = sum_a F[a] * (ctx . W[a]); even/odd dual chains ----
  f32x4 oE0 = {0.f, 0.f, 0.f, 0.f}, oE1 = {0.f, 0.f, 0.f, 0.f};
  f32x4 oO0 = {0.f, 0.f, 0.f, 0.f}, oO1 = {0.f, 0.f, 0.f, 0.f};
  const char* Wb = (const char*)LDS;
#pragma unroll
  for (int ap = 0; ap < 11; ++ap) {
    const float sE = __builtin_bit_cast(float, fvp[ap] << 16);
    const float sO = __builtin_bit_cast(float, fvp[ap] & 0xffff0000u);
    {
      const f32x2 s2 = {sE, sE};
      f32x2 p0 = cv2[0] * s2, p1 = cv2[1] * s2, p2 = cv2[2] * s2, p3 = cv2[3] * s2;
      int lo = __builtin_amdgcn_cvt_pk_fp8_f32(p0[0], p0[1], 0, 0);
      lo = __builtin_amdgcn_cvt_pk_fp8_f32(p1[0], p1[1], lo, 1);
      int hi = __builtin_amdgcn_cvt_pk_fp8_f32(p2[0], p2[1], 0, 0);
      hi = __builtin_amdgcn_cvt_pk_fp8_f32(p3[0], p3[1], hi, 1);
      long av = (long)(((unsigned long long)(unsigned int)hi << 32) | (unsigned int)lo);
      long w0 = *(const long*)(Wb + ap * 2048 + l * 8);
      long w1 = *(const long*)(Wb + ap * 2048 + 512 + l * 8);
      oE0 = __builtin_amdgcn_mfma_f32_16x16x32_fp8_fp8(av, w0, oE0, 0, 0, 0);
      oE1 = __builtin_amdgcn_mfma_f32_16x16x32_fp8_fp8(av, w1, oE1, 0, 0, 0);
    }
    {
      const f32x2 s2 = {sO, sO};
      f32x2 p0 = cv2[0] * s2, p1 = cv2[1] * s2, p2 = cv2[2] * s2, p3 = cv2[3] * s2;
      int lo = __builtin_amdgcn_cvt_pk_fp8_f32(p0[0], p0[1], 0, 0);
      lo = __builtin_amdgcn_cvt_pk_fp8_f32(p1[0], p1[1], lo, 1);
      int hi = __builtin_amdgcn_cvt_pk_fp8_f32(p2[0], p2[1], 0, 0);
      hi = __builtin_amdgcn_cvt_pk_fp8_f32(p3[0], p3[1], hi, 1);
      long av = (long)(((unsigned long long)(unsigned int)hi << 32) | (unsigned int)lo);
      long w0 = *(const long*)(Wb + ap * 2048 + 1024 + l * 8);
      long w1 = *(const long*)(Wb + ap * 2048 + 1536 + l * 8);
      oO0 = __builtin_amdgcn_mfma_f32_16x16x32_fp8_fp8(av, w0, oO0, 0, 0, 0);
      oO1 = __builtin_amdgcn_mfma_f32_16x16x32_fp8_fp8(av, w1, oO1, 0, 0, 0);
    }
  }

  // ---- epilogue: expand classes -> pixel-major fp32 (2 qy-rows) ----
  float* px4 = (float*)&LDS[SLOT];  // [2][16][9]
  float* px6 = px4 + 288;           // [2][16][13]
#pragma unroll
  for (int r = 0; r < 4; ++r) {
    const float v  = oE0[r] + oO0[r] + r4;      // col l15
    const float v1 = oE1[r] + oO1[r] + r6;      // col 16+l15 (l15<6)
    const int qy = r >> 1;
    float* p4 = px4 + qy * 144;
    float* p6 = px6 + qy * 208;
    if (r & 1) {  // qx=1 -> dx=3 only
      const int px = (lg << 2) + 3;
      if (l15 < 9) p4[px * 9 + l15] = v; else p6[px * 13 + l15 - 9] = v;
      if (l15 < 6) p6[px * 13 + 7 + l15] = v1;
    } else {      // qx=0 -> dx=0,1,2
#pragma unroll
      for (int dx = 0; dx < 3; ++dx) {
        const int px = (lg << 2) + dx;
        if (l15 < 9) p4[px * 9 + l15] = v; else p6[px * 13 + l15 - 9] = v;
        if (l15 < 6) p6[px * 13 + 7 + l15] = v1;
      }
    }
  }
  WAVE_LDS_FENCE();

  // ---- writer: contiguous dwordx4 stores (fast path: full 16-px patch) ----
  const long long y4 = (long long)(y0 << 2);
  if (cw0 + 4 <= Wc) {
#pragma unroll
    for (int ry = 0; ry < 4; ++ry) {
      const int qy = (ry == 3) ? 1 : 0;
      float* o4p = out + ((y4 + ry) * Wr + (cw0 << 2)) * 9;
      float* o6p = out6 + ((y4 + ry) * Wr + (cw0 << 2)) * 13;
      if (l < 36) *(f32x4*)(o4p + (l << 2)) = *(const f32x4*)(px4 + qy * 144 + (l << 2));
      if (l < 52) *(f32x4*)(o6p + (l << 2)) = *(const f32x4*)(px6 + qy * 208 + (l << 2));
    }
  } else {  // slow path: per-pixel scalar stores with range guard
    const int px = l & 15;
    const int ry = l >> 4;
    const int qy = (ry == 3) ? 1 : 0;
    const int hrx = (cw0 << 2) + px;
    if (hrx < Wr) {
      const long long rowb = (y4 + ry) * Wr + hrx;
      float* o4 = out + rowb * 9;
      float* o6 = out6 + rowb * 13;
#pragma unroll
      for (int ch = 0; ch < 9; ++ch) o4[ch] = px4[qy * 144 + px * 9 + ch];
#pragma unroll
      for (int ch = 0; ch < 13; ++ch) o6[ch] = px6[qy * 208 + px * 13 + ch];
    }
  }
}

extern "C" void kernel_launch(void* const* d_in, const int* in_sizes, int n_in,
                              void* d_out, int out_size, void* d_ws, size_t ws_size,
                              hipStream_t stream) {
  const float* f4 = (const float*)d_in[0];
  const float* f6 = (const float*)d_in[1];
  const int* ph = (const int*)d_in[2];
  const int* pw = (const int*)d_in[3];
  const float* wagg = (const float*)d_in[4];
  const float* wtp = (const float*)d_in[5];
  float* out = (float*)d_out;
  unsigned short* wsu = (unsigned short*)d_ws;

  long long HW = (long long)in_sizes[0] / 9;
  long long tail = (long long)out_size - 2;

  eq_setup<<<104, 256, 0, stream>>>(wagg, wtp, ph, pw, out, tail, wsu);

  int S = (int)(sqrt((double)HW) + 0.5);
  long long nb;
  if ((long long)S * S == HW) {
    nb = (long long)((S + 31) / 32) * S;  // square image (the bench case)
  } else {
    nb = HW;  // conservative cover; excess blocks exit before the barrier
  }
  eq_main<<<(int)nb, 512, 0, stream>>>(f4, f6, ph, pw, wsu, out);
}